// Round 15
// baseline (106.280 us; speedup 1.0000x reference)
//
#include <hip/hip_runtime.h>
#include <cstdint>
#include <cstddef>

// ---------- problem constants ----------
#define BB   16
#define NN   4096
#define SS   1024
#define D1   128
#define D2   256
#define CIN  384
#define C0   256
#define C1   128
#define MM   (BB*NN)          // 65536
#define NBLK (MM/128)         // 512 gemm blocks

typedef __attribute__((ext_vector_type(8))) short short8;
typedef __attribute__((ext_vector_type(4))) float f32x4;

__device__ __forceinline__ float b2f(unsigned short h) {
    union { unsigned int u; float f; } x; x.u = ((unsigned int)h) << 16; return x.f;
}
__device__ __forceinline__ unsigned short f2b(float f) {
    union { float f; unsigned int u; } x; x.f = f;
    unsigned int r = x.u + 0x7FFFu + ((x.u >> 16) & 1u);
    return (unsigned short)(r >> 16);
}

#define GLD16(g, l) __builtin_amdgcn_global_load_lds( \
    (const __attribute__((address_space(1))) void*)(g), \
    (__attribute__((address_space(3))) void*)(l), 16, 0, 0)

// sorted-triple merge: (a0<=a1<=a2) x (b0<=b1<=b2) -> top-3 of union (exact for
// distinct keys). 6 f64 min/max.
#define MRG3(k0, k1, k2, a0, a1, a2, b0, b1, b2) do { \
    double _y0 = fmax(a0, b0); k0 = fmin(a0, b0); \
    double _x1 = fmin(a1, b1); k1 = fmin(_y0, _x1); \
    double _z  = fmax(_y0, _x1); k2 = fmin(_z, fmin(a2, b2)); \
} while (0)

// sorted top-3 insert of key k into chain (c0<=c1<=c2): 5 f64 min/max
#define INS3(k, q0, q1, q2) do { \
    double _t0 = fmin((k), q0), _h0 = fmax((k), q0); \
    double _t1 = fmin(_h0, q1), _h1 = fmax(_h0, q1); \
    q2 = fmin(_h1, q2); q0 = _t0; q1 = _t1; \
} while (0)

// ---------- knn v8: half-candidate blocks, f64 packed keys, 4 ILP chains ----------
// Distance = naive (p-q)^2 (bit-identical to passing rounds). key =
// double(hi = f32 d bits, lo = idx): nonneg d => f64 compare == (d, idx)
// lexicographic == stable argsort order. 4 independent insert chains halve the
// serial f64 dep chain vs 2 (r14: VALUBusy 67% -> latency partially exposed).
__device__ __forceinline__ void knn_body8(const float* __restrict__ xyz1,
                                          const float* __restrict__ xyz2,
                                          double* __restrict__ trip, float* __restrict__ wtb,
                                          int kb, int t, char* smem)
{
    float4* cnd = (float4*)smem;           // [8][65] float4, chunk-padded
    const int h    = kb & 1;
    const int pb   = kb >> 1;
    const int b    = pb >> 7;
    const int bx   = pb & 127;
    const int chunk = t & 7;
    const int n    = bx * 32 + (t >> 3);

    for (int i = t; i < 512; i += 256) {
        int s = h * 512 + i;
        float qx = xyz2[((size_t)b * 3 + 0) * SS + s];
        float qy = xyz2[((size_t)b * 3 + 1) * SS + s];
        float qz = xyz2[((size_t)b * 3 + 2) * SS + s];
        cnd[(i >> 6) * 65 + (i & 63)] = make_float4(qx, qy, qz, 0.f);
    }
    __syncthreads();

    const float px = xyz1[((size_t)b * 3 + 0) * NN + n];
    const float py = xyz1[((size_t)b * 3 + 1) * NN + n];
    const float pz = xyz1[((size_t)b * 3 + 2) * NN + n];

    const double INITK = __hiloint2double(0x7F7FFFFF, 0);
    double cA0 = INITK, cA1 = INITK, cA2 = INITK;
    double cB0 = INITK, cB1 = INITK, cB2 = INITK;
    double cC0 = INITK, cC1 = INITK, cC2 = INITK;
    double cD0 = INITK, cD1 = INITK, cD2 = INITK;
    const float4* cc = cnd + chunk * 65;
    const int sbase = h * 512 + chunk * 64;

#pragma unroll 2
    for (int c = 0; c < 64; c += 4) {
        {
            float4 q = cc[c];
            float dx = px - q.x, dy = py - q.y, dz = pz - q.z;
            float d = dx*dx + dy*dy + dz*dz;
            double k = __hiloint2double(__float_as_int(d), sbase + c);
            INS3(k, cA0, cA1, cA2);
        }
        {
            float4 q = cc[c + 1];
            float dx = px - q.x, dy = py - q.y, dz = pz - q.z;
            float d = dx*dx + dy*dy + dz*dz;
            double k = __hiloint2double(__float_as_int(d), sbase + c + 1);
            INS3(k, cB0, cB1, cB2);
        }
        {
            float4 q = cc[c + 2];
            float dx = px - q.x, dy = py - q.y, dz = pz - q.z;
            float d = dx*dx + dy*dy + dz*dz;
            double k = __hiloint2double(__float_as_int(d), sbase + c + 2);
            INS3(k, cC0, cC1, cC2);
        }
        {
            float4 q = cc[c + 3];
            float dx = px - q.x, dy = py - q.y, dz = pz - q.z;
            float d = dx*dx + dy*dy + dz*dz;
            double k = __hiloint2double(__float_as_int(d), sbase + c + 3);
            INS3(k, cD0, cD1, cD2);
        }
    }

    // in-lane merges: (A,B)->AB, (C,D)->CD, (AB,CD)->K (exact, keys unique)
    double ab0, ab1, ab2, cd0, cd1, cd2, K0, K1, K2;
    MRG3(ab0, ab1, ab2, cA0, cA1, cA2, cB0, cB1, cB2);
    MRG3(cd0, cd1, cd2, cC0, cC1, cC2, cD0, cD1, cD2);
    MRG3(K0, K1, K2, ab0, ab1, ab2, cd0, cd1, cd2);

    // merge across the 8 chunk lanes
#pragma unroll
    for (int r = 1; r <= 4; r <<= 1) {
        double e0 = __shfl_xor(K0, r);
        double e1 = __shfl_xor(K1, r);
        double e2 = __shfl_xor(K2, r);
        double y0 = fmax(K0, e0);
        K0 = fmin(K0, e0);
        double x1 = fmin(K1, e1);
        double nK1 = fmin(y0, x1);
        double z  = fmax(y0, x1);
        K2 = fmin(z, fmin(K2, e2));
        K1 = nK1;
    }

    if (chunk == 0) {
        size_t m = (size_t)b * NN + n;
        double* tp = trip + ((size_t)h * MM + m) * 3;
        tp[0] = K0; tp[1] = K1; tp[2] = K2;
        if (h == 0) {
            float4 q0 = cnd[0], q1 = cnd[1], q2 = cnd[2];
            float dd0, dd1, dd2;
            { float dx=px-q0.x, dy=py-q0.y, dz=pz-q0.z; dd0 = fmaxf(dx*dx+dy*dy+dz*dz, 1e-10f); }
            { float dx=px-q1.x, dy=py-q1.y, dz=pz-q1.z; dd1 = fmaxf(dx*dx+dy*dy+dz*dz, 1e-10f); }
            { float dx=px-q2.x, dy=py-q2.y, dz=pz-q2.z; dd2 = fmaxf(dx*dx+dy*dy+dz*dz, 1e-10f); }
            float r0 = 1.f/dd0, r1 = 1.f/dd1, r2 = 1.f/dd2;
            float inv = 1.f / (r0 + r1 + r2);
            wtb[m*3+0] = r0*inv; wtb[m*3+1] = r1*inv; wtb[m*3+2] = r2*inv;
        }
    }
}

__device__ __forceinline__ void transpose_body(const float* __restrict__ src,
                                               unsigned short* __restrict__ dst,
                                               int C, int Np, int dstStride,
                                               int b, int cblk, int nblk, int t, char* smem)
{
    float (*tile)[65] = (float(*)[65])smem;
    const int c0 = cblk * 64, n0 = nblk * 64;
    const int j = t & 63, i4 = t >> 6;
#pragma unroll
    for (int p = 0; p < 64; p += 4) {
        int ci = p + i4;
        tile[ci][j] = src[((size_t)b * C + c0 + ci) * Np + n0 + j];
    }
    __syncthreads();
#pragma unroll
    for (int p = 0; p < 64; p += 4) {
        int ni = p + i4;
        dst[((size_t)b * Np + n0 + ni) * dstStride + c0 + j] = f2b(tile[j][ni]);
    }
}

// ---------- mega front: knn halves + transposes + weight cvt ----------
__global__ __launch_bounds__(256) void mega_front_k(
    const float* __restrict__ xyz1, const float* __restrict__ xyz2,
    const float* __restrict__ points1, const float* __restrict__ points2,
    const float* __restrict__ w0, const float* __restrict__ w1,
    unsigned short* __restrict__ P1T, unsigned short* __restrict__ P2T,
    unsigned short* __restrict__ w0b, unsigned short* __restrict__ w1b,
    double* __restrict__ trip, float* __restrict__ wtb)
{
    __shared__ __align__(16) char smem[16640];
    const unsigned bid = blockIdx.x;
    const int g = bid / 118, r = bid % 118;
    const int t = threadIdx.x;

    if (r < 64) {
        knn_body8(xyz1, xyz2, trip, wtb, g * 64 + r, t, smem);
    } else if (r < 96) {
        int rb = g * 32 + (r - 64);
        transpose_body(points1, P1T, D1, NN, D1,
                       rb >> 7, (rb >> 6) & 1, rb & 63, t, smem);
    } else if (r < 112) {
        int rb = g * 16 + (r - 96);
        transpose_body(points2, P2T, D2, SS, D2,
                       rb >> 6, (rb >> 4) & 3, rb & 15, t, smem);
    } else {
        int rb = g * 6 + (r - 112);
        int i = rb * 256 + t;
        if (i < C0 * CIN) w0b[i] = f2b(w0[i]);
        if (i < C1 * C0)  w1b[i] = f2b(w1[i]);
    }
}

// ---------- K3: GEMM1 with interpolation fused; merges knn halves in prologue ----------
// XCD-chunked swizzle: wgid = (i%8)*64 + i/8 (proven -3us in r13).
__launch_bounds__(512, 4)
__global__ void gemm1_k(const unsigned short* __restrict__ P1T,
                        const unsigned short* __restrict__ P2T,
                        const double* __restrict__ trip, const float* __restrict__ wtb,
                        const unsigned short* __restrict__ w0b,
                        unsigned short* __restrict__ h1, float* __restrict__ part1)
{
    __shared__ unsigned short Als[128 * 64];   // [row][k] bf16, XOR-swizzled
    __shared__ unsigned short Bls[256 * 64];
    __shared__ float lsum[2][256];
    __shared__ float lsq[2][256];

    const int t = threadIdx.x;
    const int wgid = ((int)blockIdx.x % 8) * (NBLK / 8) + (int)blockIdx.x / 8;
    const int wv = t >> 6, l = t & 63, g = l >> 4, lc = l & 15;
    const int wm = wv >> 2, wn = wv & 3;
    const int m0 = wgid * 128;
    const int b  = wgid >> 5;                  // 32 blocks per batch
    const int sub = t & 7;

    const int grow = t >> 2;
    const size_t gm = (size_t)(m0 + grow);
    // merge the two knn half-triples (exact f64 merge, keys unique)
    const double* tpA = trip + gm * 3;
    const double* tpB = trip + ((size_t)MM + gm) * 3;
    double hA0 = tpA[0], hA1 = tpA[1], hA2 = tpA[2];
    double hB0 = tpB[0], hB1 = tpB[1], hB2 = tpB[2];
    double K0, K1, K2;
    MRG3(K0, K1, K2, hA0, hA1, hA2, hB0, hB1, hB2);
    const int gi0 = __double2loint(K0);
    const int gi1 = __double2loint(K1);
    const int gi2 = __double2loint(K2);
    const float gw0 = wtb[gm*3], gw1 = wtb[gm*3+1], gw2 = wtb[gm*3+2];
    const char* gp0 = (const char*)(P2T + ((size_t)b * SS + gi0) * D2) + (t & 3) * 32;
    const char* gp1 = (const char*)(P2T + ((size_t)b * SS + gi1) * D2) + (t & 3) * 32;
    const char* gp2 = (const char*)(P2T + ((size_t)b * SS + gi2) * D2) + (t & 3) * 32;
    char* gdst = (char*)Als + grow * 128;
    const int gsw = (grow & 7) << 4;

    f32x4 acc[4][4];
#pragma unroll
    for (int i = 0; i < 4; ++i)
#pragma unroll
        for (int j = 0; j < 4; ++j) acc[i][j] = (f32x4){0.f, 0.f, 0.f, 0.f};

    for (int ks = 0; ks < 6; ++ks) {
        const int k0 = ks * 64;
        __syncthreads();
        if (ks < 2) {
#pragma unroll
            for (int q = 0; q < 2; ++q) {
                int row = q * 64 + (t >> 3);
                int bco = (sub * 16) ^ ((row & 7) << 4);
                const char* src = (const char*)P1T + (((size_t)(m0 + row)) * D1 + k0) * 2 + bco;
                char* dst = (char*)Als + (q * 512 + wv * 64) * 16;
                GLD16(src, dst);
            }
        } else {
            const int cgB = (ks - 2) * 128;
#pragma unroll
            for (int h = 0; h < 2; ++h) {
                union { uint4 v; unsigned short s[8]; } a0, a1, a2, ov;
                a0.v = *(const uint4*)(gp0 + cgB + h * 16);
                a1.v = *(const uint4*)(gp1 + cgB + h * 16);
                a2.v = *(const uint4*)(gp2 + cgB + h * 16);
#pragma unroll
                for (int i = 0; i < 8; ++i)
                    ov.s[i] = f2b(gw0 * b2f(a0.s[i]) + gw1 * b2f(a1.s[i]) + gw2 * b2f(a2.s[i]));
                *(uint4*)(gdst + (((t & 3) * 32 + h * 16) ^ gsw)) = ov.v;
            }
        }
#pragma unroll
        for (int q = 0; q < 4; ++q) {      // B: 32KB
            int o = q * 64 + (t >> 3);
            int bco = (sub * 16) ^ ((o & 7) << 4);
            const char* src = (const char*)w0b + (((size_t)o) * CIN + k0) * 2 + bco;
            char* dst = (char*)Bls + (q * 512 + wv * 64) * 16;
            GLD16(src, dst);
        }
        __syncthreads();
#pragma unroll
        for (int kk = 0; kk < 2; ++kk) {
            short8 af[4], bfr[4];
#pragma unroll
            for (int fm = 0; fm < 4; ++fm) {
                int row = wm * 64 + fm * 16 + lc;
                int bcol = kk * 64 + g * 16;
                af[fm] = *(const short8*)((const char*)Als + row * 128 + (bcol ^ ((row & 7) << 4)));
            }
#pragma unroll
            for (int fn = 0; fn < 4; ++fn) {
                int o = wn * 64 + fn * 16 + lc;
                int bcol = kk * 64 + g * 16;
                bfr[fn] = *(const short8*)((const char*)Bls + o * 128 + (bcol ^ ((o & 7) << 4)));
            }
#pragma unroll
            for (int fm = 0; fm < 4; ++fm)
#pragma unroll
                for (int fn = 0; fn < 4; ++fn)
                    acc[fm][fn] = __builtin_amdgcn_mfma_f32_16x16x32_bf16(af[fm], bfr[fn], acc[fm][fn], 0, 0, 0);
        }
    }

    float s1[4] = {0,0,0,0}, s2v[4] = {0,0,0,0};
#pragma unroll
    for (int fm = 0; fm < 4; ++fm)
#pragma unroll
        for (int fn = 0; fn < 4; ++fn) {
            int row = m0 + wm * 64 + fm * 16 + g * 4;
            int col = wn * 64 + fn * 16 + lc;
#pragma unroll
            for (int j = 0; j < 4; ++j) {
                float v = acc[fm][fn][j];
                h1[((size_t)(row + j)) * C0 + col] = f2b(v);
                s1[fn] += v; s2v[fn] += v * v;
            }
        }
#pragma unroll
    for (int fn = 0; fn < 4; ++fn) {
        s1[fn] += __shfl_xor(s1[fn], 16); s1[fn] += __shfl_xor(s1[fn], 32);
        s2v[fn] += __shfl_xor(s2v[fn], 16); s2v[fn] += __shfl_xor(s2v[fn], 32);
    }
    if (l < 16) {
#pragma unroll
        for (int fn = 0; fn < 4; ++fn) {
            lsum[wm][wn * 64 + fn * 16 + l] = s1[fn];
            lsq[wm][wn * 64 + fn * 16 + l] = s2v[fn];
        }
    }
    __syncthreads();
    if (t < 256) {
        part1[(size_t)t * NBLK + wgid]        = lsum[0][t] + lsum[1][t];
        part1[(size_t)(C0 + t) * NBLK + wgid] = lsq[0][t] + lsq[1][t];
    }
}

// ---------- stats: one wave per channel, coalesced [channel][block] reads ----------
__global__ void stats_k(const float* __restrict__ part, int nblk, int C,
                        const float* __restrict__ gam, const float* __restrict__ bet,
                        float* __restrict__ sc, float* __restrict__ sh)
{
    const int w = threadIdx.x >> 6, l = threadIdx.x & 63;
    const int o = blockIdx.x * 4 + w;
    if (o >= C) return;
    float s = 0.f, q = 0.f;
    for (int i = l; i < nblk; i += 64) {
        s += part[(size_t)o * nblk + i];
        q += part[(size_t)(C + o) * nblk + i];
    }
#pragma unroll
    for (int r = 32; r; r >>= 1) { s += __shfl_xor(s, r); q += __shfl_xor(q, r); }
    if (l == 0) {
        const float inv = 1.0f / (float)MM;
        float mean = s * inv;
        float var = q * inv - mean * mean;
        float scale = gam[o] * rsqrtf(var + 1e-5f);
        sc[o] = scale;
        sh[o] = bet[o] - mean * scale;
    }
}

// ---------- K5: GEMM2; same XCD-chunked swizzle as gemm1 ----------
__launch_bounds__(256, 4)
__global__ void gemm2_k(const unsigned short* __restrict__ h1, const unsigned short* __restrict__ w1b,
                        const float* __restrict__ sc1, const float* __restrict__ sh1,
                        unsigned short* __restrict__ h2, float* __restrict__ part2)
{
    __shared__ unsigned short Als[128 * 64];
    __shared__ unsigned short Bls[128 * 64];
    __shared__ float scl[256], shl[256];
    __shared__ float lsum[2][128];
    __shared__ float lsq[2][128];

    const int t = threadIdx.x;
    const int wgid = ((int)blockIdx.x % 8) * (NBLK / 8) + (int)blockIdx.x / 8;
    const int wv = t >> 6, l = t & 63, g = l >> 4, lc = l & 15;
    const int wm = wv >> 1, wn = wv & 1;
    const int m0 = wgid * 128;
    const int sub = t & 7;

    scl[t] = sc1[t]; shl[t] = sh1[t];

    f32x4 acc[4][4];
#pragma unroll
    for (int i = 0; i < 4; ++i)
#pragma unroll
        for (int j = 0; j < 4; ++j) acc[i][j] = (f32x4){0.f, 0.f, 0.f, 0.f};

    for (int ks = 0; ks < 4; ++ks) {
        const int k0 = ks * 64;
        __syncthreads();
        uint4 r[4];
#pragma unroll
        for (int q = 0; q < 4; ++q) {
            int row = q * 32 + (t >> 3);
            r[q] = *(const uint4*)((const char*)h1 + (((size_t)(m0 + row)) * C0 + k0) * 2 + sub * 16);
        }
#pragma unroll
        for (int q = 0; q < 4; ++q) {
            int row = q * 32 + (t >> 3);
            union { uint4 v; unsigned short s[8]; } u, ov;
            u.v = r[q];
#pragma unroll
            for (int i = 0; i < 8; ++i) {
                int k = k0 + sub * 8 + i;
                float f = b2f(u.s[i]);
                ov.s[i] = f2b(fmaxf(0.0f, fmaf(scl[k], f, shl[k])));
            }
            *(uint4*)((char*)Als + row * 128 + ((sub * 16) ^ ((row & 7) << 4))) = ov.v;
        }
#pragma unroll
        for (int q = 0; q < 4; ++q) {
            int o = q * 32 + (t >> 3);
            int bco = (sub * 16) ^ ((o & 7) << 4);
            const char* src = (const char*)w1b + (((size_t)o) * C0 + k0) * 2 + bco;
            char* dst = (char*)Bls + (q * 256 + wv * 64) * 16;
            GLD16(src, dst);
        }
        __syncthreads();
#pragma unroll
        for (int kk = 0; kk < 2; ++kk) {
            short8 af[4], bfr[4];
#pragma unroll
            for (int fm = 0; fm < 4; ++fm) {
                int row = wm * 64 + fm * 16 + lc;
                int bcol = kk * 64 + g * 16;
                af[fm] = *(const short8*)((const char*)Als + row * 128 + (bcol ^ ((row & 7) << 4)));
            }
#pragma unroll
            for (int fn = 0; fn < 4; ++fn) {
                int o = wn * 64 + fn * 16 + lc;
                int bcol = kk * 64 + g * 16;
                bfr[fn] = *(const short8*)((const char*)Bls + o * 128 + (bcol ^ ((o & 7) << 4)));
            }
#pragma unroll
            for (int fm = 0; fm < 4; ++fm)
#pragma unroll
                for (int fn = 0; fn < 4; ++fn)
                    acc[fm][fn] = __builtin_amdgcn_mfma_f32_16x16x32_bf16(af[fm], bfr[fn], acc[fm][fn], 0, 0, 0);
        }
    }

    float s1[4] = {0,0,0,0}, s2v[4] = {0,0,0,0};
#pragma unroll
    for (int fm = 0; fm < 4; ++fm)
#pragma unroll
        for (int fn = 0; fn < 4; ++fn) {
            int row = m0 + wm * 64 + fm * 16 + g * 4;
            int col = wn * 64 + fn * 16 + lc;
#pragma unroll
            for (int j = 0; j < 4; ++j) {
                float v = acc[fm][fn][j];
                h2[((size_t)(row + j)) * C1 + col] = f2b(v);
                s1[fn] += v; s2v[fn] += v * v;
            }
        }
#pragma unroll
    for (int fn = 0; fn < 4; ++fn) {
        s1[fn] += __shfl_xor(s1[fn], 16); s1[fn] += __shfl_xor(s1[fn], 32);
        s2v[fn] += __shfl_xor(s2v[fn], 16); s2v[fn] += __shfl_xor(s2v[fn], 32);
    }
    if (l < 16) {
#pragma unroll
        for (int fn = 0; fn < 4; ++fn) {
            lsum[wm][wn * 64 + fn * 16 + l] = s1[fn];
            lsq[wm][wn * 64 + fn * 16 + l] = s2v[fn];
        }
    }
    __syncthreads();
    if (t < 128) {
        part2[(size_t)t * NBLK + wgid]        = lsum[0][t] + lsum[1][t];
        part2[(size_t)(C1 + t) * NBLK + wgid] = lsq[0][t] + lsq[1][t];
    }
}

// ---------- K7: final BN2+ReLU + transpose, XCD-aligned flattened grid ----------
__global__ void finalize_k(const unsigned short* __restrict__ h2,
                           const float* __restrict__ sc, const float* __restrict__ sh,
                           float* __restrict__ out)
{
    __shared__ float tile[64][65];
    const int j0b = blockIdx.x;
    const int xcd = j0b & 7, local = j0b >> 3;
    const int b = xcd * 2 + (local >> 7);
    const int rem = local & 127;
    const int o0 = (rem >> 6) * 64, n0 = (rem & 63) * 64;
    const int t = threadIdx.x, j = t & 63, i4 = t >> 6;
    const float scv = sc[o0 + j], shv = sh[o0 + j];
#pragma unroll
    for (int p = 0; p < 64; p += 4) {
        int ni = p + i4;
        float f = b2f(h2[((size_t)b * NN + n0 + ni) * C1 + o0 + j]);
        tile[ni][j] = fmaxf(0.0f, fmaf(scv, f, shv));
    }
    __syncthreads();
#pragma unroll
    for (int p = 0; p < 64; p += 4) {
        int oi = p + i4;
        out[((size_t)(b * C1 + o0 + oi)) * NN + n0 + j] = tile[j][oi];
    }
}

// ---------- launch ----------
extern "C" void kernel_launch(void* const* d_in, const int* in_sizes, int n_in,
                              void* d_out, int out_size, void* d_ws, size_t ws_size,
                              hipStream_t stream)
{
    const float* xyz1    = (const float*)d_in[0];
    const float* xyz2    = (const float*)d_in[1];
    const float* points1 = (const float*)d_in[2];
    const float* points2 = (const float*)d_in[3];
    const float* w0      = (const float*)d_in[4];
    const float* g0      = (const float*)d_in[6];
    const float* be0     = (const float*)d_in[7];
    const float* w1      = (const float*)d_in[8];
    const float* g1      = (const float*)d_in[10];
    const float* be1     = (const float*)d_in[11];
    float* out = (float*)d_out;
    char* ws = (char*)d_ws;

    unsigned short* P1T = (unsigned short*)(ws + 0);           // 16777216
    unsigned short* h1  = (unsigned short*)(ws + 16777216);    // 33554432
    unsigned short* P2T = (unsigned short*)(ws + 50331648);    // 8388608
    unsigned short* h2  = (unsigned short*)(ws + 58720256);    // 16777216
    double* trip = (double*)(ws + 75497472);                   // 3145728
    float* wtb   = (float*)(ws + 78643200);                    // 786432
    unsigned short* w0b = (unsigned short*)(ws + 79429632);    // 196608
    unsigned short* w1b = (unsigned short*)(ws + 79626240);    // 65536
    float* part1 = (float*)(ws + 79691776);                    // 1048576
    float* part2 = (float*)(ws + 80740352);                    // 524288
    float* sc1   = (float*)(ws + 81264640);
    float* sh1   = (float*)(ws + 81265664);
    float* sc2   = (float*)(ws + 81266688);
    float* sh2   = (float*)(ws + 81267712);
    // total ws needed: ~81.3 MB

    mega_front_k<<<118 * 64, 256, 0, stream>>>(xyz1, xyz2, points1, points2, w0, w1,
                                               P1T, P2T, w0b, w1b, trip, wtb);
    gemm1_k<<<MM/128, 512, 0, stream>>>(P1T, P2T, trip, wtb, w0b, h1, part1);
    stats_k<<<C0/4, 256, 0, stream>>>(part1, NBLK, C0, g0, be0, sc1, sh1);
    gemm2_k<<<MM/128, 256, 0, stream>>>(h1, w1b, sc1, sh1, h2, part2);
    stats_k<<<C1/4, 256, 0, stream>>>(part2, NBLK, C1, g1, be1, sc2, sh2);
    finalize_k<<<2048, 256, 0, stream>>>(h2, sc2, sh2, out);
}

// Round 16
// 104.120 us; speedup vs baseline: 1.0207x; 1.0207x over previous
//
#include <hip/hip_runtime.h>
#include <cstdint>
#include <cstddef>

// ---------- problem constants ----------
#define BB   16
#define NN   4096
#define SS   1024
#define D1   128
#define D2   256
#define CIN  384
#define C0   256
#define C1   128
#define MM   (BB*NN)          // 65536
#define NBLK (MM/128)         // 512 gemm blocks

typedef __attribute__((ext_vector_type(8))) short short8;
typedef __attribute__((ext_vector_type(4))) float f32x4;

__device__ __forceinline__ float b2f(unsigned short h) {
    union { unsigned int u; float f; } x; x.u = ((unsigned int)h) << 16; return x.f;
}
__device__ __forceinline__ unsigned short f2b(float f) {
    union { float f; unsigned int u; } x; x.f = f;
    unsigned int r = x.u + 0x7FFFu + ((x.u >> 16) & 1u);
    return (unsigned short)(r >> 16);
}

#define GLD16(g, l) __builtin_amdgcn_global_load_lds( \
    (const __attribute__((address_space(1))) void*)(g), \
    (__attribute__((address_space(3))) void*)(l), 16, 0, 0)

// sorted-triple merge: (a0<=a1<=a2) x (b0<=b1<=b2) -> top-3 of union (exact for
// distinct keys). 6 f64 min/max.
#define MRG3(k0, k1, k2, a0, a1, a2, b0, b1, b2) do { \
    double _y0 = fmax(a0, b0); k0 = fmin(a0, b0); \
    double _x1 = fmin(a1, b1); k1 = fmin(_y0, _x1); \
    double _z  = fmax(_y0, _x1); k2 = fmin(_z, fmin(a2, b2)); \
} while (0)

// sorted top-3 insert of key k into chain (q0<=q1<=q2): 5 f64 min/max
#define INS3(k, q0, q1, q2) do { \
    double _t0 = fmin((k), q0), _h0 = fmax((k), q0); \
    double _t1 = fmin(_h0, q1), _h1 = fmax(_h0, q1); \
    q2 = fmin(_h1, q2); q0 = _t0; q1 = _t1; \
} while (0)

// ---------- knn v9: QUARTER-candidate blocks (256 cands each), f64 keys, 2 chains ----------
// Distance = naive (p-q)^2 (bit-identical to passing rounds). key =
// double(hi = f32 d bits, lo = idx): nonneg d => f64 compare == (d, idx)
// lexicographic == stable argsort order. Quarter-split shortens the knn block
// runtime ~2x vs halves -> better CU packing and shorter kernel tail (r10 lever).
__device__ __forceinline__ void knn_body9(const float* __restrict__ xyz1,
                                          const float* __restrict__ xyz2,
                                          double* __restrict__ trip, float* __restrict__ wtb,
                                          int kb, int t, char* smem)
{
    float4* cnd = (float4*)smem;           // [8][33] float4, chunk-padded
    const int h    = kb & 3;               // candidate quarter
    const int pb   = kb >> 2;              // point-block 0..2047
    const int b    = pb >> 7;
    const int bx   = pb & 127;
    const int chunk = t & 7;
    const int n    = bx * 32 + (t >> 3);

    {
        int s = h * 256 + t;
        float qx = xyz2[((size_t)b * 3 + 0) * SS + s];
        float qy = xyz2[((size_t)b * 3 + 1) * SS + s];
        float qz = xyz2[((size_t)b * 3 + 2) * SS + s];
        cnd[(t >> 5) * 33 + (t & 31)] = make_float4(qx, qy, qz, 0.f);
    }
    __syncthreads();

    const float px = xyz1[((size_t)b * 3 + 0) * NN + n];
    const float py = xyz1[((size_t)b * 3 + 1) * NN + n];
    const float pz = xyz1[((size_t)b * 3 + 2) * NN + n];

    const double INITK = __hiloint2double(0x7F7FFFFF, 0);
    double A0 = INITK, A1 = INITK, A2 = INITK;
    double B0 = INITK, B1 = INITK, B2 = INITK;
    const float4* cc = cnd + chunk * 33;
    const int sbase = h * 256 + chunk * 32;

#pragma unroll 4
    for (int c = 0; c < 32; c += 2) {
        {
            float4 q = cc[c];
            float dx = px - q.x, dy = py - q.y, dz = pz - q.z;
            float d = dx*dx + dy*dy + dz*dz;
            double k = __hiloint2double(__float_as_int(d), sbase + c);
            INS3(k, A0, A1, A2);
        }
        {
            float4 q = cc[c + 1];
            float dx = px - q.x, dy = py - q.y, dz = pz - q.z;
            float d = dx*dx + dy*dy + dz*dz;
            double k = __hiloint2double(__float_as_int(d), sbase + c + 1);
            INS3(k, B0, B1, B2);
        }
    }

    // in-lane merge of sorted triples A,B (keys unique -> exact order)
    double K0, K1, K2;
    MRG3(K0, K1, K2, A0, A1, A2, B0, B1, B2);

    // merge across the 8 chunk lanes
#pragma unroll
    for (int r = 1; r <= 4; r <<= 1) {
        double e0 = __shfl_xor(K0, r);
        double e1 = __shfl_xor(K1, r);
        double e2 = __shfl_xor(K2, r);
        double y0 = fmax(K0, e0);
        K0 = fmin(K0, e0);
        double x1 = fmin(K1, e1);
        double nK1 = fmin(y0, x1);
        double z  = fmax(y0, x1);
        K2 = fmin(z, fmin(K2, e2));
        K1 = nK1;
    }

    if (chunk == 0) {
        size_t m = (size_t)b * NN + n;
        double* tp = trip + ((size_t)h * MM + m) * 3;
        tp[0] = K0; tp[1] = K1; tp[2] = K2;
        if (h == 0) {
            // weights: distances to s=0,1,2 (faithful to reference's unsorted-column bug)
            float4 q0 = cnd[0], q1 = cnd[1], q2 = cnd[2];
            float dd0, dd1, dd2;
            { float dx=px-q0.x, dy=py-q0.y, dz=pz-q0.z; dd0 = fmaxf(dx*dx+dy*dy+dz*dz, 1e-10f); }
            { float dx=px-q1.x, dy=py-q1.y, dz=pz-q1.z; dd1 = fmaxf(dx*dx+dy*dy+dz*dz, 1e-10f); }
            { float dx=px-q2.x, dy=py-q2.y, dz=pz-q2.z; dd2 = fmaxf(dx*dx+dy*dy+dz*dz, 1e-10f); }
            float r0 = 1.f/dd0, r1 = 1.f/dd1, r2 = 1.f/dd2;
            float inv = 1.f / (r0 + r1 + r2);
            wtb[m*3+0] = r0*inv; wtb[m*3+1] = r1*inv; wtb[m*3+2] = r2*inv;
        }
    }
}

__device__ __forceinline__ void transpose_body(const float* __restrict__ src,
                                               unsigned short* __restrict__ dst,
                                               int C, int Np, int dstStride,
                                               int b, int cblk, int nblk, int t, char* smem)
{
    float (*tile)[65] = (float(*)[65])smem;
    const int c0 = cblk * 64, n0 = nblk * 64;
    const int j = t & 63, i4 = t >> 6;
#pragma unroll
    for (int p = 0; p < 64; p += 4) {
        int ci = p + i4;
        tile[ci][j] = src[((size_t)b * C + c0 + ci) * Np + n0 + j];
    }
    __syncthreads();
#pragma unroll
    for (int p = 0; p < 64; p += 4) {
        int ni = p + i4;
        dst[((size_t)b * Np + n0 + ni) * dstStride + c0 + j] = f2b(tile[j][ni]);
    }
}

// ---------- mega front: knn quarters + transposes + weight cvt ----------
// groups of 182 blocks: 128 knn-quarter + 32 P1T + 16 P2T + 6 cvtw; 64 groups.
__global__ __launch_bounds__(256) void mega_front_k(
    const float* __restrict__ xyz1, const float* __restrict__ xyz2,
    const float* __restrict__ points1, const float* __restrict__ points2,
    const float* __restrict__ w0, const float* __restrict__ w1,
    unsigned short* __restrict__ P1T, unsigned short* __restrict__ P2T,
    unsigned short* __restrict__ w0b, unsigned short* __restrict__ w1b,
    double* __restrict__ trip, float* __restrict__ wtb)
{
    __shared__ __align__(16) char smem[16640];
    const unsigned bid = blockIdx.x;
    const int g = bid / 182, r = bid % 182;
    const int t = threadIdx.x;

    if (r < 128) {
        knn_body9(xyz1, xyz2, trip, wtb, g * 128 + r, t, smem);
    } else if (r < 160) {
        int rb = g * 32 + (r - 128);
        transpose_body(points1, P1T, D1, NN, D1,
                       rb >> 7, (rb >> 6) & 1, rb & 63, t, smem);
    } else if (r < 176) {
        int rb = g * 16 + (r - 160);
        transpose_body(points2, P2T, D2, SS, D2,
                       rb >> 6, (rb >> 4) & 3, rb & 15, t, smem);
    } else {
        int rb = g * 6 + (r - 176);
        int i = rb * 256 + t;
        if (i < C0 * CIN) w0b[i] = f2b(w0[i]);
        if (i < C1 * C0)  w1b[i] = f2b(w1[i]);
    }
}

// ---------- K3: GEMM1 with interpolation fused; merges 4 knn quarters in prologue ----------
// XCD-chunked swizzle: wgid = (i%8)*64 + i/8 (proven -3us in r13).
__launch_bounds__(512, 4)
__global__ void gemm1_k(const unsigned short* __restrict__ P1T,
                        const unsigned short* __restrict__ P2T,
                        const double* __restrict__ trip, const float* __restrict__ wtb,
                        const unsigned short* __restrict__ w0b,
                        unsigned short* __restrict__ h1, float* __restrict__ part1)
{
    __shared__ unsigned short Als[128 * 64];   // [row][k] bf16, XOR-swizzled
    __shared__ unsigned short Bls[256 * 64];
    __shared__ float lsum[2][256];
    __shared__ float lsq[2][256];

    const int t = threadIdx.x;
    const int wgid = ((int)blockIdx.x % 8) * (NBLK / 8) + (int)blockIdx.x / 8;
    const int wv = t >> 6, l = t & 63, g = l >> 4, lc = l & 15;
    const int wm = wv >> 2, wn = wv & 3;
    const int m0 = wgid * 128;
    const int b  = wgid >> 5;                  // 32 blocks per batch
    const int sub = t & 7;

    const int grow = t >> 2;
    const size_t gm = (size_t)(m0 + grow);
    // merge the 4 knn quarter-triples (exact f64 merge tree, keys unique);
    // temporaries are prologue-local (dead before K-loop) -> no spill pressure.
    double K0, K1, K2;
    {
        const double* tp0 = trip + gm * 3;
        const double* tp1 = trip + ((size_t)MM + gm) * 3;
        const double* tp2 = trip + ((size_t)2 * MM + gm) * 3;
        const double* tp3 = trip + ((size_t)3 * MM + gm) * 3;
        double a0 = tp0[0], a1 = tp0[1], a2 = tp0[2];
        double b0 = tp1[0], b1 = tp1[1], b2 = tp1[2];
        double ab0, ab1, ab2;
        MRG3(ab0, ab1, ab2, a0, a1, a2, b0, b1, b2);
        double c0 = tp2[0], c1 = tp2[1], c2 = tp2[2];
        double d0 = tp3[0], d1 = tp3[1], d2 = tp3[2];
        double cd0, cd1, cd2;
        MRG3(cd0, cd1, cd2, c0, c1, c2, d0, d1, d2);
        MRG3(K0, K1, K2, ab0, ab1, ab2, cd0, cd1, cd2);
    }
    const int gi0 = __double2loint(K0);
    const int gi1 = __double2loint(K1);
    const int gi2 = __double2loint(K2);
    const float gw0 = wtb[gm*3], gw1 = wtb[gm*3+1], gw2 = wtb[gm*3+2];
    const char* gp0 = (const char*)(P2T + ((size_t)b * SS + gi0) * D2) + (t & 3) * 32;
    const char* gp1 = (const char*)(P2T + ((size_t)b * SS + gi1) * D2) + (t & 3) * 32;
    const char* gp2 = (const char*)(P2T + ((size_t)b * SS + gi2) * D2) + (t & 3) * 32;
    char* gdst = (char*)Als + grow * 128;
    const int gsw = (grow & 7) << 4;

    f32x4 acc[4][4];
#pragma unroll
    for (int i = 0; i < 4; ++i)
#pragma unroll
        for (int j = 0; j < 4; ++j) acc[i][j] = (f32x4){0.f, 0.f, 0.f, 0.f};

    for (int ks = 0; ks < 6; ++ks) {
        const int k0 = ks * 64;
        __syncthreads();
        if (ks < 2) {
#pragma unroll
            for (int q = 0; q < 2; ++q) {
                int row = q * 64 + (t >> 3);
                int bco = (sub * 16) ^ ((row & 7) << 4);
                const char* src = (const char*)P1T + (((size_t)(m0 + row)) * D1 + k0) * 2 + bco;
                char* dst = (char*)Als + (q * 512 + wv * 64) * 16;
                GLD16(src, dst);
            }
        } else {
            const int cgB = (ks - 2) * 128;
#pragma unroll
            for (int h = 0; h < 2; ++h) {
                union { uint4 v; unsigned short s[8]; } a0u, a1u, a2u, ov;
                a0u.v = *(const uint4*)(gp0 + cgB + h * 16);
                a1u.v = *(const uint4*)(gp1 + cgB + h * 16);
                a2u.v = *(const uint4*)(gp2 + cgB + h * 16);
#pragma unroll
                for (int i = 0; i < 8; ++i)
                    ov.s[i] = f2b(gw0 * b2f(a0u.s[i]) + gw1 * b2f(a1u.s[i]) + gw2 * b2f(a2u.s[i]));
                *(uint4*)(gdst + (((t & 3) * 32 + h * 16) ^ gsw)) = ov.v;
            }
        }
#pragma unroll
        for (int q = 0; q < 4; ++q) {      // B: 32KB
            int o = q * 64 + (t >> 3);
            int bco = (sub * 16) ^ ((o & 7) << 4);
            const char* src = (const char*)w0b + (((size_t)o) * CIN + k0) * 2 + bco;
            char* dst = (char*)Bls + (q * 512 + wv * 64) * 16;
            GLD16(src, dst);
        }
        __syncthreads();
#pragma unroll
        for (int kk = 0; kk < 2; ++kk) {
            short8 af[4], bfr[4];
#pragma unroll
            for (int fm = 0; fm < 4; ++fm) {
                int row = wm * 64 + fm * 16 + lc;
                int bcol = kk * 64 + g * 16;
                af[fm] = *(const short8*)((const char*)Als + row * 128 + (bcol ^ ((row & 7) << 4)));
            }
#pragma unroll
            for (int fn = 0; fn < 4; ++fn) {
                int o = wn * 64 + fn * 16 + lc;
                int bcol = kk * 64 + g * 16;
                bfr[fn] = *(const short8*)((const char*)Bls + o * 128 + (bcol ^ ((o & 7) << 4)));
            }
#pragma unroll
            for (int fm = 0; fm < 4; ++fm)
#pragma unroll
                for (int fn = 0; fn < 4; ++fn)
                    acc[fm][fn] = __builtin_amdgcn_mfma_f32_16x16x32_bf16(af[fm], bfr[fn], acc[fm][fn], 0, 0, 0);
        }
    }

    float s1[4] = {0,0,0,0}, s2v[4] = {0,0,0,0};
#pragma unroll
    for (int fm = 0; fm < 4; ++fm)
#pragma unroll
        for (int fn = 0; fn < 4; ++fn) {
            int row = m0 + wm * 64 + fm * 16 + g * 4;
            int col = wn * 64 + fn * 16 + lc;
#pragma unroll
            for (int j = 0; j < 4; ++j) {
                float v = acc[fm][fn][j];
                h1[((size_t)(row + j)) * C0 + col] = f2b(v);
                s1[fn] += v; s2v[fn] += v * v;
            }
        }
#pragma unroll
    for (int fn = 0; fn < 4; ++fn) {
        s1[fn] += __shfl_xor(s1[fn], 16); s1[fn] += __shfl_xor(s1[fn], 32);
        s2v[fn] += __shfl_xor(s2v[fn], 16); s2v[fn] += __shfl_xor(s2v[fn], 32);
    }
    if (l < 16) {
#pragma unroll
        for (int fn = 0; fn < 4; ++fn) {
            lsum[wm][wn * 64 + fn * 16 + l] = s1[fn];
            lsq[wm][wn * 64 + fn * 16 + l] = s2v[fn];
        }
    }
    __syncthreads();
    if (t < 256) {
        part1[(size_t)t * NBLK + wgid]        = lsum[0][t] + lsum[1][t];
        part1[(size_t)(C0 + t) * NBLK + wgid] = lsq[0][t] + lsq[1][t];
    }
}

// ---------- stats: one wave per channel, coalesced [channel][block] reads ----------
__global__ void stats_k(const float* __restrict__ part, int nblk, int C,
                        const float* __restrict__ gam, const float* __restrict__ bet,
                        float* __restrict__ sc, float* __restrict__ sh)
{
    const int w = threadIdx.x >> 6, l = threadIdx.x & 63;
    const int o = blockIdx.x * 4 + w;
    if (o >= C) return;
    float s = 0.f, q = 0.f;
    for (int i = l; i < nblk; i += 64) {
        s += part[(size_t)o * nblk + i];
        q += part[(size_t)(C + o) * nblk + i];
    }
#pragma unroll
    for (int r = 32; r; r >>= 1) { s += __shfl_xor(s, r); q += __shfl_xor(q, r); }
    if (l == 0) {
        const float inv = 1.0f / (float)MM;
        float mean = s * inv;
        float var = q * inv - mean * mean;
        float scale = gam[o] * rsqrtf(var + 1e-5f);
        sc[o] = scale;
        sh[o] = bet[o] - mean * scale;
    }
}

// ---------- K5: GEMM2; same XCD-chunked swizzle as gemm1 ----------
__launch_bounds__(256, 4)
__global__ void gemm2_k(const unsigned short* __restrict__ h1, const unsigned short* __restrict__ w1b,
                        const float* __restrict__ sc1, const float* __restrict__ sh1,
                        unsigned short* __restrict__ h2, float* __restrict__ part2)
{
    __shared__ unsigned short Als[128 * 64];
    __shared__ unsigned short Bls[128 * 64];
    __shared__ float scl[256], shl[256];
    __shared__ float lsum[2][128];
    __shared__ float lsq[2][128];

    const int t = threadIdx.x;
    const int wgid = ((int)blockIdx.x % 8) * (NBLK / 8) + (int)blockIdx.x / 8;
    const int wv = t >> 6, l = t & 63, g = l >> 4, lc = l & 15;
    const int wm = wv >> 1, wn = wv & 1;
    const int m0 = wgid * 128;
    const int sub = t & 7;

    scl[t] = sc1[t]; shl[t] = sh1[t];

    f32x4 acc[4][4];
#pragma unroll
    for (int i = 0; i < 4; ++i)
#pragma unroll
        for (int j = 0; j < 4; ++j) acc[i][j] = (f32x4){0.f, 0.f, 0.f, 0.f};

    for (int ks = 0; ks < 4; ++ks) {
        const int k0 = ks * 64;
        __syncthreads();
        uint4 r[4];
#pragma unroll
        for (int q = 0; q < 4; ++q) {
            int row = q * 32 + (t >> 3);
            r[q] = *(const uint4*)((const char*)h1 + (((size_t)(m0 + row)) * C0 + k0) * 2 + sub * 16);
        }
#pragma unroll
        for (int q = 0; q < 4; ++q) {
            int row = q * 32 + (t >> 3);
            union { uint4 v; unsigned short s[8]; } u, ov;
            u.v = r[q];
#pragma unroll
            for (int i = 0; i < 8; ++i) {
                int k = k0 + sub * 8 + i;
                float f = b2f(u.s[i]);
                ov.s[i] = f2b(fmaxf(0.0f, fmaf(scl[k], f, shl[k])));
            }
            *(uint4*)((char*)Als + row * 128 + ((sub * 16) ^ ((row & 7) << 4))) = ov.v;
        }
#pragma unroll
        for (int q = 0; q < 4; ++q) {
            int o = q * 32 + (t >> 3);
            int bco = (sub * 16) ^ ((o & 7) << 4);
            const char* src = (const char*)w1b + (((size_t)o) * C0 + k0) * 2 + bco;
            char* dst = (char*)Bls + (q * 256 + wv * 64) * 16;
            GLD16(src, dst);
        }
        __syncthreads();
#pragma unroll
        for (int kk = 0; kk < 2; ++kk) {
            short8 af[4], bfr[4];
#pragma unroll
            for (int fm = 0; fm < 4; ++fm) {
                int row = wm * 64 + fm * 16 + lc;
                int bcol = kk * 64 + g * 16;
                af[fm] = *(const short8*)((const char*)Als + row * 128 + (bcol ^ ((row & 7) << 4)));
            }
#pragma unroll
            for (int fn = 0; fn < 4; ++fn) {
                int o = wn * 64 + fn * 16 + lc;
                int bcol = kk * 64 + g * 16;
                bfr[fn] = *(const short8*)((const char*)Bls + o * 128 + (bcol ^ ((o & 7) << 4)));
            }
#pragma unroll
            for (int fm = 0; fm < 4; ++fm)
#pragma unroll
                for (int fn = 0; fn < 4; ++fn)
                    acc[fm][fn] = __builtin_amdgcn_mfma_f32_16x16x32_bf16(af[fm], bfr[fn], acc[fm][fn], 0, 0, 0);
        }
    }

    float s1[4] = {0,0,0,0}, s2v[4] = {0,0,0,0};
#pragma unroll
    for (int fm = 0; fm < 4; ++fm)
#pragma unroll
        for (int fn = 0; fn < 4; ++fn) {
            int row = m0 + wm * 64 + fm * 16 + g * 4;
            int col = wn * 64 + fn * 16 + lc;
#pragma unroll
            for (int j = 0; j < 4; ++j) {
                float v = acc[fm][fn][j];
                h2[((size_t)(row + j)) * C1 + col] = f2b(v);
                s1[fn] += v; s2v[fn] += v * v;
            }
        }
#pragma unroll
    for (int fn = 0; fn < 4; ++fn) {
        s1[fn] += __shfl_xor(s1[fn], 16); s1[fn] += __shfl_xor(s1[fn], 32);
        s2v[fn] += __shfl_xor(s2v[fn], 16); s2v[fn] += __shfl_xor(s2v[fn], 32);
    }
    if (l < 16) {
#pragma unroll
        for (int fn = 0; fn < 4; ++fn) {
            lsum[wm][wn * 64 + fn * 16 + l] = s1[fn];
            lsq[wm][wn * 64 + fn * 16 + l] = s2v[fn];
        }
    }
    __syncthreads();
    if (t < 128) {
        part2[(size_t)t * NBLK + wgid]        = lsum[0][t] + lsum[1][t];
        part2[(size_t)(C1 + t) * NBLK + wgid] = lsq[0][t] + lsq[1][t];
    }
}

// ---------- K7: final BN2+ReLU + transpose, XCD-aligned flattened grid ----------
__global__ void finalize_k(const unsigned short* __restrict__ h2,
                           const float* __restrict__ sc, const float* __restrict__ sh,
                           float* __restrict__ out)
{
    __shared__ float tile[64][65];
    const int j0b = blockIdx.x;
    const int xcd = j0b & 7, local = j0b >> 3;
    const int b = xcd * 2 + (local >> 7);
    const int rem = local & 127;
    const int o0 = (rem >> 6) * 64, n0 = (rem & 63) * 64;
    const int t = threadIdx.x, j = t & 63, i4 = t >> 6;
    const float scv = sc[o0 + j], shv = sh[o0 + j];
#pragma unroll
    for (int p = 0; p < 64; p += 4) {
        int ni = p + i4;
        float f = b2f(h2[((size_t)b * NN + n0 + ni) * C1 + o0 + j]);
        tile[ni][j] = fmaxf(0.0f, fmaf(scv, f, shv));
    }
    __syncthreads();
#pragma unroll
    for (int p = 0; p < 64; p += 4) {
        int oi = p + i4;
        out[((size_t)(b * C1 + o0 + oi)) * NN + n0 + j] = tile[j][oi];
    }
}

// ---------- launch ----------
extern "C" void kernel_launch(void* const* d_in, const int* in_sizes, int n_in,
                              void* d_out, int out_size, void* d_ws, size_t ws_size,
                              hipStream_t stream)
{
    const float* xyz1    = (const float*)d_in[0];
    const float* xyz2    = (const float*)d_in[1];
    const float* points1 = (const float*)d_in[2];
    const float* points2 = (const float*)d_in[3];
    const float* w0      = (const float*)d_in[4];
    const float* g0      = (const float*)d_in[6];
    const float* be0     = (const float*)d_in[7];
    const float* w1      = (const float*)d_in[8];
    const float* g1      = (const float*)d_in[10];
    const float* be1     = (const float*)d_in[11];
    float* out = (float*)d_out;
    char* ws = (char*)d_ws;

    unsigned short* P1T = (unsigned short*)(ws + 0);           // 16777216
    unsigned short* h1  = (unsigned short*)(ws + 16777216);    // 33554432
    unsigned short* P2T = (unsigned short*)(ws + 50331648);    // 8388608
    unsigned short* h2  = (unsigned short*)(ws + 58720256);    // 16777216
    double* trip = (double*)(ws + 75497472);                   // 4*65536*3*8 = 6291456
    float* wtb   = (float*)(ws + 81788928);                    // 786432
    unsigned short* w0b = (unsigned short*)(ws + 82575360);    // 196608
    unsigned short* w1b = (unsigned short*)(ws + 82771968);    // 65536
    float* part1 = (float*)(ws + 82837504);                    // 1048576
    float* part2 = (float*)(ws + 83886080);                    // 524288
    float* sc1   = (float*)(ws + 84410368);
    float* sh1   = (float*)(ws + 84411392);
    float* sc2   = (float*)(ws + 84412416);
    float* sh2   = (float*)(ws + 84413440);
    // total ws needed: ~84.4 MB

    mega_front_k<<<182 * 64, 256, 0, stream>>>(xyz1, xyz2, points1, points2, w0, w1,
                                               P1T, P2T, w0b, w1b, trip, wtb);
    gemm1_k<<<MM/128, 512, 0, stream>>>(P1T, P2T, trip, wtb, w0b, h1, part1);
    stats_k<<<C0/4, 256, 0, stream>>>(part1, NBLK, C0, g0, be0, sc1, sh1);
    gemm2_k<<<MM/128, 256, 0, stream>>>(h1, w1b, sc1, sh1, h2, part2);
    stats_k<<<C1/4, 256, 0, stream>>>(part2, NBLK, C1, g1, be1, sc2, sh2);
    finalize_k<<<2048, 256, 0, stream>>>(h2, sc2, sh2, out);
}

// Round 17
// 103.980 us; speedup vs baseline: 1.0221x; 1.0013x over previous
//
#include <hip/hip_runtime.h>
#include <cstdint>
#include <cstddef>

// ---------- problem constants ----------
#define BB   16
#define NN   4096
#define SS   1024
#define D1   128
#define D2   256
#define CIN  384
#define C0   256
#define C1   128
#define MM   (BB*NN)          // 65536
#define NBLK (MM/128)         // 512 gemm blocks

typedef __attribute__((ext_vector_type(8))) short short8;
typedef __attribute__((ext_vector_type(4))) float f32x4;
typedef __attribute__((ext_vector_type(2))) float f32x2;

__device__ __forceinline__ float b2f(unsigned short h) {
    union { unsigned int u; float f; } x; x.u = ((unsigned int)h) << 16; return x.f;
}
__device__ __forceinline__ unsigned short f2b(float f) {
    union { float f; unsigned int u; } x; x.f = f;
    unsigned int r = x.u + 0x7FFFu + ((x.u >> 16) & 1u);
    return (unsigned short)(r >> 16);
}

#define GLD16(g, l) __builtin_amdgcn_global_load_lds( \
    (const __attribute__((address_space(1))) void*)(g), \
    (__attribute__((address_space(3))) void*)(l), 16, 0, 0)

// sorted-triple merge: (a0<=a1<=a2) x (b0<=b1<=b2) -> top-3 of union (exact for
// distinct keys). 6 f64 min/max.
#define MRG3(k0, k1, k2, a0, a1, a2, b0, b1, b2) do { \
    double _y0 = fmax(a0, b0); k0 = fmin(a0, b0); \
    double _x1 = fmin(a1, b1); k1 = fmin(_y0, _x1); \
    double _z  = fmax(_y0, _x1); k2 = fmin(_z, fmin(a2, b2)); \
} while (0)

// sorted top-3 insert of key k into chain (q0<=q1<=q2): 5 f64 min/max
#define INS3(k, q0, q1, q2) do { \
    double _t0 = fmin((k), q0), _h0 = fmax((k), q0); \
    double _t1 = fmin(_h0, q1), _h1 = fmax(_h0, q1); \
    q2 = fmin(_h1, q2); q0 = _t0; q1 = _t1; \
} while (0)

// ---------- knn v10: quarter blocks + packed-f32 (v_pk) pair distances ----------
// Candidate coords in LDS as SoA pairs [8 chunks][3 comps][34 pad]: per A/B pair
// one ds_read_b64 per component, distances via float2 ops (pk_sub/pk_fma lowering;
// per-element IEEE identical to the scalar form -> selection unchanged).
// key = double(hi = f32 d bits, lo = idx) -> f64 compare == stable argsort order.
__device__ __forceinline__ void knn_body10(const float* __restrict__ xyz1,
                                           const float* __restrict__ xyz2,
                                           double* __restrict__ trip, float* __restrict__ wtb,
                                           int kb, int t, char* smem)
{
    float* cf = (float*)smem;              // [8][3][34]
    const int h    = kb & 3;               // candidate quarter
    const int pb   = kb >> 2;              // point-block 0..2047
    const int b    = pb >> 7;
    const int bx   = pb & 127;
    const int chunk = t & 7;
    const int n    = bx * 32 + (t >> 3);

    {
        int s = h * 256 + t;
        int co = t >> 5, pos = t & 31;
        cf[(co * 3 + 0) * 34 + pos] = xyz2[((size_t)b * 3 + 0) * SS + s];
        cf[(co * 3 + 1) * 34 + pos] = xyz2[((size_t)b * 3 + 1) * SS + s];
        cf[(co * 3 + 2) * 34 + pos] = xyz2[((size_t)b * 3 + 2) * SS + s];
    }
    __syncthreads();

    const float px = xyz1[((size_t)b * 3 + 0) * NN + n];
    const float py = xyz1[((size_t)b * 3 + 1) * NN + n];
    const float pz = xyz1[((size_t)b * 3 + 2) * NN + n];
    const f32x2 pxv = {px, px}, pyv = {py, py}, pzv = {pz, pz};

    const double INITK = __hiloint2double(0x7F7FFFFF, 0);
    double A0 = INITK, A1 = INITK, A2 = INITK;
    double B0 = INITK, B1 = INITK, B2 = INITK;
    const float* cx = cf + (chunk * 3 + 0) * 34;
    const float* cy = cf + (chunk * 3 + 1) * 34;
    const float* cz = cf + (chunk * 3 + 2) * 34;
    const int sbase = h * 256 + chunk * 32;

#pragma unroll 4
    for (int c = 0; c < 32; c += 2) {
        f32x2 qx = *(const f32x2*)(cx + c);
        f32x2 qy = *(const f32x2*)(cy + c);
        f32x2 qz = *(const f32x2*)(cz + c);
        f32x2 dx = pxv - qx, dy = pyv - qy, dz = pzv - qz;
        f32x2 d = dx * dx + dy * dy + dz * dz;
        double kA = __hiloint2double(__float_as_int(d.x), sbase + c);
        double kB = __hiloint2double(__float_as_int(d.y), sbase + c + 1);
        INS3(kA, A0, A1, A2);
        INS3(kB, B0, B1, B2);
    }

    // in-lane merge of sorted triples A,B (keys unique -> exact order)
    double K0, K1, K2;
    MRG3(K0, K1, K2, A0, A1, A2, B0, B1, B2);

    // merge across the 8 chunk lanes
#pragma unroll
    for (int r = 1; r <= 4; r <<= 1) {
        double e0 = __shfl_xor(K0, r);
        double e1 = __shfl_xor(K1, r);
        double e2 = __shfl_xor(K2, r);
        double y0 = fmax(K0, e0);
        K0 = fmin(K0, e0);
        double x1 = fmin(K1, e1);
        double nK1 = fmin(y0, x1);
        double z  = fmax(y0, x1);
        K2 = fmin(z, fmin(K2, e2));
        K1 = nK1;
    }

    if (chunk == 0) {
        size_t m = (size_t)b * NN + n;
        double* tp = trip + ((size_t)h * MM + m) * 3;
        tp[0] = K0; tp[1] = K1; tp[2] = K2;
        if (h == 0) {
            // weights: distances to s=0,1,2 (faithful to reference's unsorted-column bug)
            float dd0, dd1, dd2;
            { float dx=px-cx[0], dy=py-cy[0], dz=pz-cz[0]; dd0 = fmaxf(dx*dx+dy*dy+dz*dz, 1e-10f); }
            { float dx=px-cx[1], dy=py-cy[1], dz=pz-cz[1]; dd1 = fmaxf(dx*dx+dy*dy+dz*dz, 1e-10f); }
            { float dx=px-cx[2], dy=py-cy[2], dz=pz-cz[2]; dd2 = fmaxf(dx*dx+dy*dy+dz*dz, 1e-10f); }
            float r0 = 1.f/dd0, r1 = 1.f/dd1, r2 = 1.f/dd2;
            float inv = 1.f / (r0 + r1 + r2);
            wtb[m*3+0] = r0*inv; wtb[m*3+1] = r1*inv; wtb[m*3+2] = r2*inv;
        }
    }
}

__device__ __forceinline__ void transpose_body(const float* __restrict__ src,
                                               unsigned short* __restrict__ dst,
                                               int C, int Np, int dstStride,
                                               int b, int cblk, int nblk, int t, char* smem)
{
    float (*tile)[65] = (float(*)[65])smem;
    const int c0 = cblk * 64, n0 = nblk * 64;
    const int j = t & 63, i4 = t >> 6;
#pragma unroll
    for (int p = 0; p < 64; p += 4) {
        int ci = p + i4;
        tile[ci][j] = src[((size_t)b * C + c0 + ci) * Np + n0 + j];
    }
    __syncthreads();
#pragma unroll
    for (int p = 0; p < 64; p += 4) {
        int ni = p + i4;
        dst[((size_t)b * Np + n0 + ni) * dstStride + c0 + j] = f2b(tile[j][ni]);
    }
}

// ---------- mega front: knn quarters + transposes + weight cvt ----------
// groups of 182 blocks: 128 knn-quarter + 32 P1T + 16 P2T + 6 cvtw; 64 groups.
__global__ __launch_bounds__(256) void mega_front_k(
    const float* __restrict__ xyz1, const float* __restrict__ xyz2,
    const float* __restrict__ points1, const float* __restrict__ points2,
    const float* __restrict__ w0, const float* __restrict__ w1,
    unsigned short* __restrict__ P1T, unsigned short* __restrict__ P2T,
    unsigned short* __restrict__ w0b, unsigned short* __restrict__ w1b,
    double* __restrict__ trip, float* __restrict__ wtb)
{
    __shared__ __align__(16) char smem[16640];
    const unsigned bid = blockIdx.x;
    const int g = bid / 182, r = bid % 182;
    const int t = threadIdx.x;

    if (r < 128) {
        knn_body10(xyz1, xyz2, trip, wtb, g * 128 + r, t, smem);
    } else if (r < 160) {
        int rb = g * 32 + (r - 128);
        transpose_body(points1, P1T, D1, NN, D1,
                       rb >> 7, (rb >> 6) & 1, rb & 63, t, smem);
    } else if (r < 176) {
        int rb = g * 16 + (r - 160);
        transpose_body(points2, P2T, D2, SS, D2,
                       rb >> 6, (rb >> 4) & 3, rb & 15, t, smem);
    } else {
        int rb = g * 6 + (r - 176);
        int i = rb * 256 + t;
        if (i < C0 * CIN) w0b[i] = f2b(w0[i]);
        if (i < C1 * C0)  w1b[i] = f2b(w1[i]);
    }
}

// ---------- K3: GEMM1 with interpolation fused; merges 4 knn quarters in prologue ----------
// XCD-chunked swizzle: wgid = (i%8)*64 + i/8 (proven -3us in r13).
__launch_bounds__(512, 4)
__global__ void gemm1_k(const unsigned short* __restrict__ P1T,
                        const unsigned short* __restrict__ P2T,
                        const double* __restrict__ trip, const float* __restrict__ wtb,
                        const unsigned short* __restrict__ w0b,
                        unsigned short* __restrict__ h1, float* __restrict__ part1)
{
    __shared__ unsigned short Als[128 * 64];   // [row][k] bf16, XOR-swizzled
    __shared__ unsigned short Bls[256 * 64];
    __shared__ float lsum[2][256];
    __shared__ float lsq[2][256];

    const int t = threadIdx.x;
    const int wgid = ((int)blockIdx.x % 8) * (NBLK / 8) + (int)blockIdx.x / 8;
    const int wv = t >> 6, l = t & 63, g = l >> 4, lc = l & 15;
    const int wm = wv >> 2, wn = wv & 3;
    const int m0 = wgid * 128;
    const int b  = wgid >> 5;                  // 32 blocks per batch
    const int sub = t & 7;

    const int grow = t >> 2;
    const size_t gm = (size_t)(m0 + grow);
    // merge the 4 knn quarter-triples (exact f64 merge tree, keys unique);
    // temporaries are prologue-local (dead before K-loop) -> no spill pressure.
    double K0, K1, K2;
    {
        const double* tp0 = trip + gm * 3;
        const double* tp1 = trip + ((size_t)MM + gm) * 3;
        const double* tp2 = trip + ((size_t)2 * MM + gm) * 3;
        const double* tp3 = trip + ((size_t)3 * MM + gm) * 3;
        double a0 = tp0[0], a1 = tp0[1], a2 = tp0[2];
        double b0 = tp1[0], b1 = tp1[1], b2 = tp1[2];
        double ab0, ab1, ab2;
        MRG3(ab0, ab1, ab2, a0, a1, a2, b0, b1, b2);
        double c0 = tp2[0], c1 = tp2[1], c2 = tp2[2];
        double d0 = tp3[0], d1 = tp3[1], d2 = tp3[2];
        double cd0, cd1, cd2;
        MRG3(cd0, cd1, cd2, c0, c1, c2, d0, d1, d2);
        MRG3(K0, K1, K2, ab0, ab1, ab2, cd0, cd1, cd2);
    }
    const int gi0 = __double2loint(K0);
    const int gi1 = __double2loint(K1);
    const int gi2 = __double2loint(K2);
    const float gw0 = wtb[gm*3], gw1 = wtb[gm*3+1], gw2 = wtb[gm*3+2];
    const char* gp0 = (const char*)(P2T + ((size_t)b * SS + gi0) * D2) + (t & 3) * 32;
    const char* gp1 = (const char*)(P2T + ((size_t)b * SS + gi1) * D2) + (t & 3) * 32;
    const char* gp2 = (const char*)(P2T + ((size_t)b * SS + gi2) * D2) + (t & 3) * 32;
    char* gdst = (char*)Als + grow * 128;
    const int gsw = (grow & 7) << 4;

    f32x4 acc[4][4];
#pragma unroll
    for (int i = 0; i < 4; ++i)
#pragma unroll
        for (int j = 0; j < 4; ++j) acc[i][j] = (f32x4){0.f, 0.f, 0.f, 0.f};

    for (int ks = 0; ks < 6; ++ks) {
        const int k0 = ks * 64;
        __syncthreads();
        if (ks < 2) {
#pragma unroll
            for (int q = 0; q < 2; ++q) {
                int row = q * 64 + (t >> 3);
                int bco = (sub * 16) ^ ((row & 7) << 4);
                const char* src = (const char*)P1T + (((size_t)(m0 + row)) * D1 + k0) * 2 + bco;
                char* dst = (char*)Als + (q * 512 + wv * 64) * 16;
                GLD16(src, dst);
            }
        } else {
            const int cgB = (ks - 2) * 128;
#pragma unroll
            for (int h = 0; h < 2; ++h) {
                union { uint4 v; unsigned short s[8]; } a0u, a1u, a2u, ov;
                a0u.v = *(const uint4*)(gp0 + cgB + h * 16);
                a1u.v = *(const uint4*)(gp1 + cgB + h * 16);
                a2u.v = *(const uint4*)(gp2 + cgB + h * 16);
#pragma unroll
                for (int i = 0; i < 8; ++i)
                    ov.s[i] = f2b(gw0 * b2f(a0u.s[i]) + gw1 * b2f(a1u.s[i]) + gw2 * b2f(a2u.s[i]));
                *(uint4*)(gdst + (((t & 3) * 32 + h * 16) ^ gsw)) = ov.v;
            }
        }
#pragma unroll
        for (int q = 0; q < 4; ++q) {      // B: 32KB
            int o = q * 64 + (t >> 3);
            int bco = (sub * 16) ^ ((o & 7) << 4);
            const char* src = (const char*)w0b + (((size_t)o) * CIN + k0) * 2 + bco;
            char* dst = (char*)Bls + (q * 512 + wv * 64) * 16;
            GLD16(src, dst);
        }
        __syncthreads();
#pragma unroll
        for (int kk = 0; kk < 2; ++kk) {
            short8 af[4], bfr[4];
#pragma unroll
            for (int fm = 0; fm < 4; ++fm) {
                int row = wm * 64 + fm * 16 + lc;
                int bcol = kk * 64 + g * 16;
                af[fm] = *(const short8*)((const char*)Als + row * 128 + (bcol ^ ((row & 7) << 4)));
            }
#pragma unroll
            for (int fn = 0; fn < 4; ++fn) {
                int o = wn * 64 + fn * 16 + lc;
                int bcol = kk * 64 + g * 16;
                bfr[fn] = *(const short8*)((const char*)Bls + o * 128 + (bcol ^ ((o & 7) << 4)));
            }
#pragma unroll
            for (int fm = 0; fm < 4; ++fm)
#pragma unroll
                for (int fn = 0; fn < 4; ++fn)
                    acc[fm][fn] = __builtin_amdgcn_mfma_f32_16x16x32_bf16(af[fm], bfr[fn], acc[fm][fn], 0, 0, 0);
        }
    }

    float s1[4] = {0,0,0,0}, s2v[4] = {0,0,0,0};
#pragma unroll
    for (int fm = 0; fm < 4; ++fm)
#pragma unroll
        for (int fn = 0; fn < 4; ++fn) {
            int row = m0 + wm * 64 + fm * 16 + g * 4;
            int col = wn * 64 + fn * 16 + lc;
#pragma unroll
            for (int j = 0; j < 4; ++j) {
                float v = acc[fm][fn][j];
                h1[((size_t)(row + j)) * C0 + col] = f2b(v);
                s1[fn] += v; s2v[fn] += v * v;
            }
        }
#pragma unroll
    for (int fn = 0; fn < 4; ++fn) {
        s1[fn] += __shfl_xor(s1[fn], 16); s1[fn] += __shfl_xor(s1[fn], 32);
        s2v[fn] += __shfl_xor(s2v[fn], 16); s2v[fn] += __shfl_xor(s2v[fn], 32);
    }
    if (l < 16) {
#pragma unroll
        for (int fn = 0; fn < 4; ++fn) {
            lsum[wm][wn * 64 + fn * 16 + l] = s1[fn];
            lsq[wm][wn * 64 + fn * 16 + l] = s2v[fn];
        }
    }
    __syncthreads();
    if (t < 256) {
        part1[(size_t)t * NBLK + wgid]        = lsum[0][t] + lsum[1][t];
        part1[(size_t)(C0 + t) * NBLK + wgid] = lsq[0][t] + lsq[1][t];
    }
}

// ---------- stats: one wave per channel, coalesced [channel][block] reads ----------
__global__ void stats_k(const float* __restrict__ part, int nblk, int C,
                        const float* __restrict__ gam, const float* __restrict__ bet,
                        float* __restrict__ sc, float* __restrict__ sh)
{
    const int w = threadIdx.x >> 6, l = threadIdx.x & 63;
    const int o = blockIdx.x * 4 + w;
    if (o >= C) return;
    float s = 0.f, q = 0.f;
    for (int i = l; i < nblk; i += 64) {
        s += part[(size_t)o * nblk + i];
        q += part[(size_t)(C + o) * nblk + i];
    }
#pragma unroll
    for (int r = 32; r; r >>= 1) { s += __shfl_xor(s, r); q += __shfl_xor(q, r); }
    if (l == 0) {
        const float inv = 1.0f / (float)MM;
        float mean = s * inv;
        float var = q * inv - mean * mean;
        float scale = gam[o] * rsqrtf(var + 1e-5f);
        sc[o] = scale;
        sh[o] = bet[o] - mean * scale;
    }
}

// ---------- K5: GEMM2; same XCD-chunked swizzle as gemm1 ----------
__launch_bounds__(256, 4)
__global__ void gemm2_k(const unsigned short* __restrict__ h1, const unsigned short* __restrict__ w1b,
                        const float* __restrict__ sc1, const float* __restrict__ sh1,
                        unsigned short* __restrict__ h2, float* __restrict__ part2)
{
    __shared__ unsigned short Als[128 * 64];
    __shared__ unsigned short Bls[128 * 64];
    __shared__ float scl[256], shl[256];
    __shared__ float lsum[2][128];
    __shared__ float lsq[2][128];

    const int t = threadIdx.x;
    const int wgid = ((int)blockIdx.x % 8) * (NBLK / 8) + (int)blockIdx.x / 8;
    const int wv = t >> 6, l = t & 63, g = l >> 4, lc = l & 15;
    const int wm = wv >> 1, wn = wv & 1;
    const int m0 = wgid * 128;
    const int sub = t & 7;

    scl[t] = sc1[t]; shl[t] = sh1[t];

    f32x4 acc[4][4];
#pragma unroll
    for (int i = 0; i < 4; ++i)
#pragma unroll
        for (int j = 0; j < 4; ++j) acc[i][j] = (f32x4){0.f, 0.f, 0.f, 0.f};

    for (int ks = 0; ks < 4; ++ks) {
        const int k0 = ks * 64;
        __syncthreads();
        uint4 r[4];
#pragma unroll
        for (int q = 0; q < 4; ++q) {
            int row = q * 32 + (t >> 3);
            r[q] = *(const uint4*)((const char*)h1 + (((size_t)(m0 + row)) * C0 + k0) * 2 + sub * 16);
        }
#pragma unroll
        for (int q = 0; q < 4; ++q) {
            int row = q * 32 + (t >> 3);
            union { uint4 v; unsigned short s[8]; } u, ov;
            u.v = r[q];
#pragma unroll
            for (int i = 0; i < 8; ++i) {
                int k = k0 + sub * 8 + i;
                float f = b2f(u.s[i]);
                ov.s[i] = f2b(fmaxf(0.0f, fmaf(scl[k], f, shl[k])));
            }
            *(uint4*)((char*)Als + row * 128 + ((sub * 16) ^ ((row & 7) << 4))) = ov.v;
        }
#pragma unroll
        for (int q = 0; q < 4; ++q) {
            int o = q * 32 + (t >> 3);
            int bco = (sub * 16) ^ ((o & 7) << 4);
            const char* src = (const char*)w1b + (((size_t)o) * C0 + k0) * 2 + bco;
            char* dst = (char*)Bls + (q * 256 + wv * 64) * 16;
            GLD16(src, dst);
        }
        __syncthreads();
#pragma unroll
        for (int kk = 0; kk < 2; ++kk) {
            short8 af[4], bfr[4];
#pragma unroll
            for (int fm = 0; fm < 4; ++fm) {
                int row = wm * 64 + fm * 16 + lc;
                int bcol = kk * 64 + g * 16;
                af[fm] = *(const short8*)((const char*)Als + row * 128 + (bcol ^ ((row & 7) << 4)));
            }
#pragma unroll
            for (int fn = 0; fn < 4; ++fn) {
                int o = wn * 64 + fn * 16 + lc;
                int bcol = kk * 64 + g * 16;
                bfr[fn] = *(const short8*)((const char*)Bls + o * 128 + (bcol ^ ((o & 7) << 4)));
            }
#pragma unroll
            for (int fm = 0; fm < 4; ++fm)
#pragma unroll
                for (int fn = 0; fn < 4; ++fn)
                    acc[fm][fn] = __builtin_amdgcn_mfma_f32_16x16x32_bf16(af[fm], bfr[fn], acc[fm][fn], 0, 0, 0);
        }
    }

    float s1[4] = {0,0,0,0}, s2v[4] = {0,0,0,0};
#pragma unroll
    for (int fm = 0; fm < 4; ++fm)
#pragma unroll
        for (int fn = 0; fn < 4; ++fn) {
            int row = m0 + wm * 64 + fm * 16 + g * 4;
            int col = wn * 64 + fn * 16 + lc;
#pragma unroll
            for (int j = 0; j < 4; ++j) {
                float v = acc[fm][fn][j];
                h2[((size_t)(row + j)) * C1 + col] = f2b(v);
                s1[fn] += v; s2v[fn] += v * v;
            }
        }
#pragma unroll
    for (int fn = 0; fn < 4; ++fn) {
        s1[fn] += __shfl_xor(s1[fn], 16); s1[fn] += __shfl_xor(s1[fn], 32);
        s2v[fn] += __shfl_xor(s2v[fn], 16); s2v[fn] += __shfl_xor(s2v[fn], 32);
    }
    if (l < 16) {
#pragma unroll
        for (int fn = 0; fn < 4; ++fn) {
            lsum[wm][wn * 64 + fn * 16 + l] = s1[fn];
            lsq[wm][wn * 64 + fn * 16 + l] = s2v[fn];
        }
    }
    __syncthreads();
    if (t < 128) {
        part2[(size_t)t * NBLK + wgid]        = lsum[0][t] + lsum[1][t];
        part2[(size_t)(C1 + t) * NBLK + wgid] = lsq[0][t] + lsq[1][t];
    }
}

// ---------- K7: final BN2+ReLU + transpose, XCD-aligned grid, widened accesses ----------
__global__ void finalize_k(const unsigned short* __restrict__ h2,
                           const float* __restrict__ sc, const float* __restrict__ sh,
                           float* __restrict__ out)
{
    __shared__ float tile[64][65];
    const int j0b = blockIdx.x;
    const int xcd = j0b & 7, local = j0b >> 3;
    const int b = xcd * 2 + (local >> 7);
    const int rem = local & 127;
    const int o0 = (rem >> 6) * 64, n0 = (rem & 63) * 64;
    const int t = threadIdx.x;

    // phase 1: ushort2 h2 reads, BN2+ReLU -> tile[n][o]
    const int j2 = (t & 31) * 2;
    const int i8 = t >> 5;
    const float sA = sc[o0 + j2], sB = sc[o0 + j2 + 1];
    const float hA = sh[o0 + j2], hB = sh[o0 + j2 + 1];
#pragma unroll
    for (int p = 0; p < 64; p += 8) {
        int ni = p + i8;
        unsigned int u = *(const unsigned int*)(h2 + ((size_t)b * NN + n0 + ni) * C1 + o0 + j2);
        float f0 = b2f((unsigned short)(u & 0xFFFFu));
        float f1 = b2f((unsigned short)(u >> 16));
        tile[ni][j2]     = fmaxf(0.0f, fmaf(sA, f0, hA));
        tile[ni][j2 + 1] = fmaxf(0.0f, fmaf(sB, f1, hB));
    }
    __syncthreads();

    // phase 2: float2 stores (lane owns an n-pair; 8B x 32 lanes contiguous)
    const int n2 = (t & 31) * 2;
    const int o8 = t >> 5;
#pragma unroll
    for (int p = 0; p < 64; p += 8) {
        int oi = p + o8;
        float2 v = make_float2(tile[n2][oi], tile[n2 + 1][oi]);
        *(float2*)(out + ((size_t)(b * C1 + o0 + oi)) * NN + n0 + n2) = v;
    }
}

// ---------- launch ----------
extern "C" void kernel_launch(void* const* d_in, const int* in_sizes, int n_in,
                              void* d_out, int out_size, void* d_ws, size_t ws_size,
                              hipStream_t stream)
{
    const float* xyz1    = (const float*)d_in[0];
    const float* xyz2    = (const float*)d_in[1];
    const float* points1 = (const float*)d_in[2];
    const float* points2 = (const float*)d_in[3];
    const float* w0      = (const float*)d_in[4];
    const float* g0      = (const float*)d_in[6];
    const float* be0     = (const float*)d_in[7];
    const float* w1      = (const float*)d_in[8];
    const float* g1      = (const float*)d_in[10];
    const float* be1     = (const float*)d_in[11];
    float* out = (float*)d_out;
    char* ws = (char*)d_ws;

    unsigned short* P1T = (unsigned short*)(ws + 0);           // 16777216
    unsigned short* h1  = (unsigned short*)(ws + 16777216);    // 33554432
    unsigned short* P2T = (unsigned short*)(ws + 50331648);    // 8388608
    unsigned short* h2  = (unsigned short*)(ws + 58720256);    // 16777216
    double* trip = (double*)(ws + 75497472);                   // 4*65536*3*8 = 6291456
    float* wtb   = (float*)(ws + 81788928);                    // 786432
    unsigned short* w0b = (unsigned short*)(ws + 82575360);    // 196608
    unsigned short* w1b = (unsigned short*)(ws + 82771968);    // 65536
    float* part1 = (float*)(ws + 82837504);                    // 1048576
    float* part2 = (float*)(ws + 83886080);                    // 524288
    float* sc1   = (float*)(ws + 84410368);
    float* sh1   = (float*)(ws + 84411392);
    float* sc2   = (float*)(ws + 84412416);
    float* sh2   = (float*)(ws + 84413440);
    // total ws needed: ~84.4 MB

    mega_front_k<<<182 * 64, 256, 0, stream>>>(xyz1, xyz2, points1, points2, w0, w1,
                                               P1T, P2T, w0b, w1b, trip, wtb);
    gemm1_k<<<MM/128, 512, 0, stream>>>(P1T, P2T, trip, wtb, w0b, h1, part1);
    stats_k<<<C0/4, 256, 0, stream>>>(part1, NBLK, C0, g0, be0, sc1, sh1);
    gemm2_k<<<MM/128, 256, 0, stream>>>(h1, w1b, sc1, sh1, h2, part2);
    stats_k<<<C1/4, 256, 0, stream>>>(part2, NBLK, C1, g1, be1, sc2, sh2);
    finalize_k<<<2048, 256, 0, stream>>>(h2, sc2, sh2, out);
}